// Round 1
// baseline (648.675 us; speedup 1.0000x reference)
//
#include <hip/hip_runtime.h>
#include <math.h>

// Problem constants (match reference)
#define BB 4
#define NN 2048
#define CC 64
#define HH 512
#define WW 512
#define GS 8
#define HG 64
#define WG 64
#define MM 4096          // HG*WG
#define EPSF 1e-8f
#define NUM_NEG 4
#define MARGINF 1.0f

// ---------------------------------------------------------------------------
// Kernel 1: average-pool desc2 (B x C x H x W) over 8x8 blocks -> cells (B x M x C)
// One wave per (b, c, gy); lane = gx. Fully coalesced reads (wave covers 2 KB/row).
// ---------------------------------------------------------------------------
__global__ __launch_bounds__(256) void pool_kernel(const float* __restrict__ desc2,
                                                   float* __restrict__ cells) {
    int wave = blockIdx.x * 4 + (threadIdx.x >> 6);   // 0 .. B*C*HG-1
    int lane = threadIdx.x & 63;                      // gx
    int gy = wave & 63;
    int c  = (wave >> 6) & 63;
    int b  = wave >> 12;
    const float* base = desc2 + (((size_t)b * CC + c) * HH + (size_t)gy * GS) * WW;
    float s = 0.f;
#pragma unroll
    for (int yy = 0; yy < GS; ++yy) {
        const float4* rp = (const float4*)(base + (size_t)yy * WW) + lane * 2;
        float4 a = rp[0];
        float4 d = rp[1];
        s += a.x + a.y + a.z + a.w + d.x + d.y + d.z + d.w;
    }
    s *= (1.0f / 64.0f);
    cells[((size_t)b * MM + (size_t)gy * WG + lane) * CC + c] = s;
}

// ---------------------------------------------------------------------------
// Kernel 2: L2-normalize each cell (in place) and record cn = ||cell_norm||^2.
// One wave per cell; lane = channel.
// ---------------------------------------------------------------------------
__global__ __launch_bounds__(256) void normcells_kernel(float* __restrict__ cells,
                                                        float* __restrict__ cn) {
    int wave = blockIdx.x * 4 + (threadIdx.x >> 6);   // 0 .. B*M-1
    int lane = threadIdx.x & 63;
    size_t idx = (size_t)wave * CC + lane;
    float v = cells[idx];
    float ss = v * v;
#pragma unroll
    for (int off = 32; off; off >>= 1) ss += __shfl_xor(ss, off, 64);
    float norm = sqrtf(ss);
    float inv = 1.0f / (norm + EPSF);
    cells[idx] = v * inv;
    if (lane == 0) {
        float r = norm * inv;
        cn[wave] = r * r;
    }
}

// ---------------------------------------------------------------------------
// Kernel 3: bilinear-sample positives, normalize, d_pos and an per keypoint.
// One wave per keypoint; lane = channel.
// ---------------------------------------------------------------------------
__global__ __launch_bounds__(256) void pos_kernel(const float* __restrict__ w_kp1,
                                                  const float* __restrict__ kp1_desc,
                                                  const float* __restrict__ desc2,
                                                  float* __restrict__ dpos,
                                                  float* __restrict__ an) {
    int kp = blockIdx.x * 4 + (threadIdx.x >> 6);     // b*N + n
    int lane = threadIdx.x & 63;
    int b = kp >> 11;                                 // / N
    float wx = w_kp1[(size_t)kp * 2 + 0];
    float wy = w_kp1[(size_t)kp * 2 + 1];
    float x = fminf(fmaxf(wx, 0.f), (float)(WW - 1));
    float y = fminf(fmaxf(wy, 0.f), (float)(HH - 1));
    float x0 = floorf(x), y0 = floorf(y);
    int x0i = (int)x0, y0i = (int)y0;
    int x1i = min(x0i + 1, WW - 1);
    int y1i = min(y0i + 1, HH - 1);
    float fx = x - x0, fy = y - y0;
    const float* p = desc2 + ((size_t)b * CC + lane) * (size_t)HH * WW;
    float v00 = p[(size_t)y0i * WW + x0i];
    float v01 = p[(size_t)y0i * WW + x1i];
    float v10 = p[(size_t)y1i * WW + x0i];
    float v11 = p[(size_t)y1i * WW + x1i];
    float pos = (1.f - fy) * (1.f - fx) * v00 + (1.f - fy) * fx * v01
              + fy * (1.f - fx) * v10 + fy * fx * v11;
    float ss = pos * pos;
#pragma unroll
    for (int off = 32; off; off >>= 1) ss += __shfl_xor(ss, off, 64);
    float posn = pos / (sqrtf(ss) + EPSF);
    float kd = kp1_desc[(size_t)kp * CC + lane];
    float diff = kd - posn;
    float dd = diff * diff;
    float aa = kd * kd;
#pragma unroll
    for (int off = 32; off; off >>= 1) {
        dd += __shfl_xor(dd, off, 64);
        aa += __shfl_xor(aa, off, 64);
    }
    if (lane == 0) {
        dpos[kp] = sqrtf(dd + EPSF);
        an[kp] = aa;
    }
}

// ---------------------------------------------------------------------------
// Kernel 4: fused distance matrix + center-radius mask + top-4 smallest + loss.
// Block = 256 threads = 32 keypoints x 8 cell-partitions. Each thread owns one
// keypoint's descriptor in registers (64 VGPRs); cells staged in LDS tiles of
// 32 with +4 pad (8 distinct float4 addrs/wave -> all 32 banks, 8-way lane
// broadcast is free). Branchless sorted insert maintains running top-4.
// ---------------------------------------------------------------------------
#define KPB 32
#define MT  32
#define LDSTR 68   // 64 + 4 pad floats

__global__ __launch_bounds__(256) void loss_kernel(const float* __restrict__ cells,
                                                   const float* __restrict__ cn,
                                                   const float* __restrict__ kp1_desc,
                                                   const float* __restrict__ w_kp1,
                                                   const float* __restrict__ dpos,
                                                   const float* __restrict__ an,
                                                   float* __restrict__ partials) {
    __shared__ float tile[MT * LDSTR];
    __shared__ float cn_t[MT];
    __shared__ float top_lds[KPB][8][4];
    __shared__ float kl[KPB];

    int b  = blockIdx.y;
    int n0 = blockIdx.x * KPB;
    int tid = threadIdx.x;
    int kp_l = tid >> 3;          // 0..31
    int part = tid & 7;           // 0..7
    int kp = b * NN + n0 + kp_l;

    // keypoint descriptor into registers (8-way redundant load, L1/L2-cached)
    float4 dsc[16];
    const float4* drow = (const float4*)(kp1_desc + (size_t)kp * CC);
#pragma unroll
    for (int i = 0; i < 16; ++i) dsc[i] = drow[i];

    float wx = w_kp1[(size_t)kp * 2 + 0];
    float wy = w_kp1[(size_t)kp * 2 + 1];
    float a_n = an[kp];

    float t0 = 1e30f, t1 = 1e30f, t2 = 1e30f, t3 = 1e30f;

    const float* cellb = cells + (size_t)b * MM * CC;
    const float* cnb   = cn + (size_t)b * MM;

    for (int t = 0; t < MM / MT; ++t) {
        __syncthreads();
        // stage MT cells x 64 floats = 512 float4, 2 per thread
#pragma unroll
        for (int i = 0; i < 2; ++i) {
            int f = tid + i * 256;
            int row = f >> 4, c4 = f & 15;
            float4 v = ((const float4*)(cellb + (size_t)(t * MT + row) * CC))[c4];
            *((float4*)&tile[row * LDSTR + c4 * 4]) = v;
        }
        if (tid < MT) cn_t[tid] = cnb[t * MT + tid];
        __syncthreads();

#pragma unroll
        for (int cs = 0; cs < MT / 8; ++cs) {
            int ct = cs * 8 + part;
            const float* cr = &tile[ct * LDSTR];
            float dot = 0.f;
#pragma unroll
            for (int k = 0; k < 16; ++k) {
                float4 cv = *((const float4*)(cr + k * 4));
                dot += dsc[k].x * cv.x + dsc[k].y * cv.y
                     + dsc[k].z * cv.z + dsc[k].w * cv.w;
            }
            int m = t * MT + ct;
            float cx = (float)((m & 63) * 8 + 4);
            float cy = (float)((m >> 6) * 8 + 4);
            float dx = wx - cx, dy = wy - cy;
            float geo2 = dx * dx + dy * dy;
            float d2 = fmaxf(a_n + cn_t[ct] - 2.f * dot, 0.f) + EPSF;
            float d = sqrtf(d2);
            d = (geo2 <= 64.0f) ? 1e6f : d;
            // branchless sorted insert (t0<=t1<=t2<=t3)
            t3 = fminf(t3, fmaxf(t2, d));
            t2 = fminf(t2, fmaxf(t1, d));
            t1 = fminf(t1, fmaxf(t0, d));
            t0 = fminf(t0, d);
        }
    }

    top_lds[kp_l][part][0] = t0;
    top_lds[kp_l][part][1] = t1;
    top_lds[kp_l][part][2] = t2;
    top_lds[kp_l][part][3] = t3;
    __syncthreads();

    if (tid < KPB) {
        float m0 = 1e30f, m1 = 1e30f, m2 = 1e30f, m3 = 1e30f;
#pragma unroll
        for (int p = 0; p < 8; ++p) {
#pragma unroll
            for (int j = 0; j < 4; ++j) {
                float d = top_lds[tid][p][j];
                m3 = fminf(m3, fmaxf(m2, d));
                m2 = fminf(m2, fmaxf(m1, d));
                m1 = fminf(m1, fmaxf(m0, d));
                m0 = fminf(m0, d);
            }
        }
        float dp = dpos[b * NN + n0 + tid];
        float l = fmaxf(dp - m0 + MARGINF, 0.f)
                + fmaxf(dp - m1 + MARGINF, 0.f)
                + fmaxf(dp - m2 + MARGINF, 0.f)
                + fmaxf(dp - m3 + MARGINF, 0.f);
        kl[tid] = l;
    }
    __syncthreads();
    if (tid == 0) {
        float s = 0.f;
#pragma unroll
        for (int i = 0; i < KPB; ++i) s += kl[i];
        partials[blockIdx.y * (NN / KPB) + blockIdx.x] = s;
    }
}

// ---------------------------------------------------------------------------
// Kernel 5: reduce 256 block partials -> mean -> d_out[0]
// ---------------------------------------------------------------------------
__global__ __launch_bounds__(256) void finalize_kernel(const float* __restrict__ partials,
                                                       float* __restrict__ out) {
    __shared__ float s4[4];
    int tid = threadIdx.x;
    float v = partials[tid];
#pragma unroll
    for (int off = 32; off; off >>= 1) v += __shfl_xor(v, off, 64);
    if ((tid & 63) == 0) s4[tid >> 6] = v;
    __syncthreads();
    if (tid == 0) {
        float tot = s4[0] + s4[1] + s4[2] + s4[3];
        out[0] = tot * (1.0f / (float)(BB * NN * NUM_NEG));
    }
}

extern "C" void kernel_launch(void* const* d_in, const int* in_sizes, int n_in,
                              void* d_out, int out_size, void* d_ws, size_t ws_size,
                              hipStream_t stream) {
    // inputs: 0=kp1 (unused), 1=w_kp1, 2=kp1_desc, 3=desc2, 4=homo12 (unused)
    const float* w_kp1    = (const float*)d_in[1];
    const float* kp1_desc = (const float*)d_in[2];
    const float* desc2    = (const float*)d_in[3];
    float* out = (float*)d_out;

    float* ws = (float*)d_ws;
    float* cells    = ws;                         // B*M*C = 1,048,576 floats
    float* cn       = cells + (size_t)BB * MM * CC;  // B*M = 16384
    float* dpos     = cn + (size_t)BB * MM;          // B*N = 8192
    float* an       = dpos + (size_t)BB * NN;        // B*N = 8192
    float* partials = an + (size_t)BB * NN;          // 256

    // 1. pool: B*C*HG waves = 16384 -> 4096 blocks of 4 waves
    pool_kernel<<<dim3(4096), dim3(256), 0, stream>>>(desc2, cells);
    // 2. normalize cells: B*M waves = 16384 -> 4096 blocks
    normcells_kernel<<<dim3(4096), dim3(256), 0, stream>>>(cells, cn);
    // 3. positives: B*N waves = 8192 -> 2048 blocks
    pos_kernel<<<dim3(2048), dim3(256), 0, stream>>>(w_kp1, kp1_desc, desc2, dpos, an);
    // 4. fused loss: (N/KPB, B) = (64, 4) blocks
    loss_kernel<<<dim3(NN / KPB, BB), dim3(256), 0, stream>>>(
        cells, cn, kp1_desc, w_kp1, dpos, an, partials);
    // 5. finalize
    finalize_kernel<<<dim3(1), dim3(256), 0, stream>>>(partials, out);
}

// Round 2
// 423.296 us; speedup vs baseline: 1.5324x; 1.5324x over previous
//
#include <hip/hip_runtime.h>
#include <math.h>

// Problem constants (match reference)
#define BB 4
#define NN 2048
#define CC 64
#define HH 512
#define WW 512
#define GS 8
#define HG 64
#define WG 64
#define MM 4096          // HG*WG
#define EPSF 1e-8f
#define NUM_NEG 4
#define MARGINF 1.0f

typedef __attribute__((ext_vector_type(8))) short short8;   // 8 bf16 (4 VGPRs)
typedef __attribute__((ext_vector_type(4))) float f32x4;

__device__ __forceinline__ unsigned short f32_to_bf16_rne(float x) {
    unsigned int u = __float_as_uint(x);
    u += 0x7fffu + ((u >> 16) & 1u);
    return (unsigned short)(u >> 16);
}

// ---------------------------------------------------------------------------
// Kernel 1: average-pool desc2 (B x C x H x W) over 8x8 blocks -> cells (B x M x C)
// One wave per (b, c, gy); lane = gx. Coalesced reads.
// ---------------------------------------------------------------------------
__global__ __launch_bounds__(256) void pool_kernel(const float* __restrict__ desc2,
                                                   float* __restrict__ cells) {
    int wave = blockIdx.x * 4 + (threadIdx.x >> 6);   // 0 .. B*C*HG-1
    int lane = threadIdx.x & 63;                      // gx
    int gy = wave & 63;
    int c  = (wave >> 6) & 63;
    int b  = wave >> 12;
    const float* base = desc2 + (((size_t)b * CC + c) * HH + (size_t)gy * GS) * WW;
    float s = 0.f;
#pragma unroll
    for (int yy = 0; yy < GS; ++yy) {
        const float4* rp = (const float4*)(base + (size_t)yy * WW) + lane * 2;
        float4 a = rp[0];
        float4 d = rp[1];
        s += a.x + a.y + a.z + a.w + d.x + d.y + d.z + d.w;
    }
    s *= (1.0f / 64.0f);
    cells[((size_t)b * MM + (size_t)gy * WG + lane) * CC + c] = s;
}

// ---------------------------------------------------------------------------
// Kernel 2: L2-normalize each cell, write fp32 (unused downstream except cn),
// bf16 copy for MFMA, and cn = ||cell_norm||^2. One wave per cell; lane = ch.
// ---------------------------------------------------------------------------
__global__ __launch_bounds__(256) void normcells_kernel(const float* __restrict__ cells,
                                                        unsigned short* __restrict__ cells_bf,
                                                        float* __restrict__ cn) {
    int wave = blockIdx.x * 4 + (threadIdx.x >> 6);   // 0 .. B*M-1
    int lane = threadIdx.x & 63;
    size_t idx = (size_t)wave * CC + lane;
    float v = cells[idx];
    float ss = v * v;
#pragma unroll
    for (int off = 32; off; off >>= 1) ss += __shfl_xor(ss, off, 64);
    float norm = sqrtf(ss);
    float inv = 1.0f / (norm + EPSF);
    float vn = v * inv;
    cells_bf[idx] = f32_to_bf16_rne(vn);
    if (lane == 0) {
        float r = norm * inv;
        cn[wave] = r * r;
    }
}

// ---------------------------------------------------------------------------
// Kernel 3: bilinear-sample positives, d_pos, an, bf16 copy of kp1_desc.
// One wave per keypoint; lane = channel.
// ---------------------------------------------------------------------------
__global__ __launch_bounds__(256) void pos_kernel(const float* __restrict__ w_kp1,
                                                  const float* __restrict__ kp1_desc,
                                                  const float* __restrict__ desc2,
                                                  float* __restrict__ dpos,
                                                  float* __restrict__ an,
                                                  unsigned short* __restrict__ kp_bf) {
    int kp = blockIdx.x * 4 + (threadIdx.x >> 6);     // b*N + n
    int lane = threadIdx.x & 63;
    int b = kp >> 11;                                 // / N
    float wx = w_kp1[(size_t)kp * 2 + 0];
    float wy = w_kp1[(size_t)kp * 2 + 1];
    float x = fminf(fmaxf(wx, 0.f), (float)(WW - 1));
    float y = fminf(fmaxf(wy, 0.f), (float)(HH - 1));
    float x0 = floorf(x), y0 = floorf(y);
    int x0i = (int)x0, y0i = (int)y0;
    int x1i = min(x0i + 1, WW - 1);
    int y1i = min(y0i + 1, HH - 1);
    float fx = x - x0, fy = y - y0;
    const float* p = desc2 + ((size_t)b * CC + lane) * (size_t)HH * WW;
    float v00 = p[(size_t)y0i * WW + x0i];
    float v01 = p[(size_t)y0i * WW + x1i];
    float v10 = p[(size_t)y1i * WW + x0i];
    float v11 = p[(size_t)y1i * WW + x1i];
    float pos = (1.f - fy) * (1.f - fx) * v00 + (1.f - fy) * fx * v01
              + fy * (1.f - fx) * v10 + fy * fx * v11;
    float ss = pos * pos;
#pragma unroll
    for (int off = 32; off; off >>= 1) ss += __shfl_xor(ss, off, 64);
    float posn = pos / (sqrtf(ss) + EPSF);
    float kd = kp1_desc[(size_t)kp * CC + lane];
    kp_bf[(size_t)kp * CC + lane] = f32_to_bf16_rne(kd);
    float diff = kd - posn;
    float dd = diff * diff;
    float aa = kd * kd;
#pragma unroll
    for (int off = 32; off; off >>= 1) {
        dd += __shfl_xor(dd, off, 64);
        aa += __shfl_xor(aa, off, 64);
    }
    if (lane == 0) {
        dpos[kp] = sqrtf(dd + EPSF);
        an[kp] = aa;
    }
}

// ---------------------------------------------------------------------------
// Kernel 4: MFMA distance matrix + mask + per-partition top-4 (in d^2 space).
// Block = 4 waves = 64 kps; each wave: 16 kps x 512-cell partition.
// Per 16x16 tile: 2x v_mfma_f32_16x16x32_bf16 (K=64) + fp32 epilogue.
// D layout: col = lane&15 (cell), row = (lane>>4)*4 + reg (kp)  [m89/m91].
// A/B frag: X[idx=lane&15][k = (lane>>4)*8 + j], j=0..7 contiguous bf16.
// ---------------------------------------------------------------------------
#define INS4(T0,T1,T2,T3,V) do { \
    T3 = fminf(T3, fmaxf(T2, V)); \
    T2 = fminf(T2, fmaxf(T1, V)); \
    T1 = fminf(T1, fmaxf(T0, V)); \
    T0 = fminf(T0, V); } while (0)

__global__ __launch_bounds__(256) void loss_mfma_kernel(const unsigned short* __restrict__ cells_bf,
                                                        const float* __restrict__ cn,
                                                        const unsigned short* __restrict__ kp_bf,
                                                        const float* __restrict__ w_kp1,
                                                        const float* __restrict__ an,
                                                        float* __restrict__ cand) {
    __shared__ float mg[4][16][16][4];   // [wave][kp_local][cell-lane][4] = 16 KB

    int b   = blockIdx.y;
    int kpg = blockIdx.x >> 3;           // 0..31  (group of 64 kps)
    int p   = blockIdx.x & 7;            // cell partition 0..7 (512 cells each)
    int tid = threadIdx.x;
    int w   = tid >> 6;                  // wave 0..3
    int L   = tid & 63;
    int q   = L >> 4;                    // quad
    int r   = L & 15;

    int n0 = kpg * 64 + w * 16;          // kp-tile base (within batch)

    // A fragments (kp descriptors), loaded once: row n0+r, k = q*8.. and +32
    const short8* arow = (const short8*)(kp_bf + (size_t)(b * NN + n0 + r) * CC);
    short8 afrag0 = arow[q];
    short8 afrag1 = arow[q + 4];

    // per-reg kp scalars: kp = n0 + q*4 + j
    const float4* anp = (const float4*)(an + (size_t)b * NN + n0 + q * 4);
    float4 an4 = anp[0];
    const float4* wp = (const float4*)(w_kp1 + (size_t)(b * NN + n0 + q * 4) * 2);
    float4 wA = wp[0], wB = wp[1];
    float wx0 = wA.x, wy0 = wA.y, wx1 = wA.z, wy1 = wA.w;
    float wx2 = wB.x, wy2 = wB.y, wx3 = wB.z, wy3 = wB.w;

    float t00 = 1e30f, t01 = 1e30f, t02 = 1e30f, t03 = 1e30f;
    float t10 = 1e30f, t11 = 1e30f, t12 = 1e30f, t13 = 1e30f;
    float t20 = 1e30f, t21 = 1e30f, t22 = 1e30f, t23 = 1e30f;
    float t30 = 1e30f, t31 = 1e30f, t32 = 1e30f, t33 = 1e30f;

    const unsigned short* cellb = cells_bf + (size_t)b * MM * CC;
    const float* cnb = cn + (size_t)b * MM;

#pragma unroll 4
    for (int t = 0; t < 32; ++t) {
        int m0 = p * 512 + t * 16;
        const short8* brow = (const short8*)(cellb + (size_t)(m0 + r) * CC);
        short8 bfrag0 = brow[q];
        short8 bfrag1 = brow[q + 4];
        float cnl = cnb[m0 + r];
        float cxl = (float)(((m0 & 63) + r) * 8 + 4);
        float cyl = (float)((m0 >> 6) * 8 + 4);

        f32x4 acc = {0.f, 0.f, 0.f, 0.f};
        acc = __builtin_amdgcn_mfma_f32_16x16x32_bf16(afrag0, bfrag0, acc, 0, 0, 0);
        acc = __builtin_amdgcn_mfma_f32_16x16x32_bf16(afrag1, bfrag1, acc, 0, 0, 0);

        // reg j -> kp n0 + q*4 + j, cell m0 + r
        {
            float d2 = fmaf(-2.f, acc[0], an4.x + cnl);
            float dx = wx0 - cxl, dy = wy0 - cyl;
            float v = (fmaf(dx, dx, dy * dy) <= 64.f) ? 1e12f : d2;
            INS4(t00, t01, t02, t03, v);
        }
        {
            float d2 = fmaf(-2.f, acc[1], an4.y + cnl);
            float dx = wx1 - cxl, dy = wy1 - cyl;
            float v = (fmaf(dx, dx, dy * dy) <= 64.f) ? 1e12f : d2;
            INS4(t10, t11, t12, t13, v);
        }
        {
            float d2 = fmaf(-2.f, acc[2], an4.z + cnl);
            float dx = wx2 - cxl, dy = wy2 - cyl;
            float v = (fmaf(dx, dx, dy * dy) <= 64.f) ? 1e12f : d2;
            INS4(t20, t21, t22, t23, v);
        }
        {
            float d2 = fmaf(-2.f, acc[3], an4.w + cnl);
            float dx = wx3 - cxl, dy = wy3 - cyl;
            float v = (fmaf(dx, dx, dy * dy) <= 64.f) ? 1e12f : d2;
            INS4(t30, t31, t32, t33, v);
        }
    }

    // stash per-lane top4 lists: kp_local = q*4+j, cell-class = r
    {
        float4 v;
        v.x = t00; v.y = t01; v.z = t02; v.w = t03;
        *(float4*)&mg[w][q * 4 + 0][r][0] = v;
        v.x = t10; v.y = t11; v.z = t12; v.w = t13;
        *(float4*)&mg[w][q * 4 + 1][r][0] = v;
        v.x = t20; v.y = t21; v.z = t22; v.w = t23;
        *(float4*)&mg[w][q * 4 + 2][r][0] = v;
        v.x = t30; v.y = t31; v.z = t32; v.w = t33;
        *(float4*)&mg[w][q * 4 + 3][r][0] = v;
    }
    __syncthreads();

    // merge 16 lists of 4 per (wave, kp_local): 4 threads each take 4 lists,
    // then butterfly-merge across the 4 threads.
    int w2  = tid >> 6;
    int kl  = (tid >> 2) & 15;
    int seg = tid & 3;
    float m0v = 1e30f, m1v = 1e30f, m2v = 1e30f, m3v = 1e30f;
#pragma unroll
    for (int i = 0; i < 4; ++i) {
        float4 v = *(const float4*)&mg[w2][kl][seg * 4 + i][0];
        INS4(m0v, m1v, m2v, m3v, v.x);
        INS4(m0v, m1v, m2v, m3v, v.y);
        INS4(m0v, m1v, m2v, m3v, v.z);
        INS4(m0v, m1v, m2v, m3v, v.w);
    }
#pragma unroll
    for (int step = 1; step <= 2; step <<= 1) {
        float p0 = __shfl_xor(m0v, step, 64);
        float p1 = __shfl_xor(m1v, step, 64);
        float p2 = __shfl_xor(m2v, step, 64);
        float p3 = __shfl_xor(m3v, step, 64);
        INS4(m0v, m1v, m2v, m3v, p0);
        INS4(m0v, m1v, m2v, m3v, p1);
        INS4(m0v, m1v, m2v, m3v, p2);
        INS4(m0v, m1v, m2v, m3v, p3);
    }
    if (seg == 0) {
        size_t kp = (size_t)b * NN + kpg * 64 + w2 * 16 + kl;
        float4 v; v.x = m0v; v.y = m1v; v.z = m2v; v.w = m3v;
        *(float4*)(cand + kp * 32 + p * 4) = v;
    }
}

// ---------------------------------------------------------------------------
// Kernel 5: per-kp merge of 8 partitions, sqrt, loss, block partial sums.
// One thread per keypoint.
// ---------------------------------------------------------------------------
__global__ __launch_bounds__(256) void merge_kernel(const float* __restrict__ cand,
                                                    const float* __restrict__ dpos,
                                                    float* __restrict__ partials) {
    __shared__ float s4[4];
    int kp = blockIdx.x * 256 + threadIdx.x;
    float m0 = 1e30f, m1 = 1e30f, m2 = 1e30f, m3 = 1e30f;
    const float4* cp = (const float4*)(cand + (size_t)kp * 32);
#pragma unroll
    for (int i = 0; i < 8; ++i) {
        float4 v = cp[i];
        INS4(m0, m1, m2, m3, v.x);
        INS4(m0, m1, m2, m3, v.y);
        INS4(m0, m1, m2, m3, v.z);
        INS4(m0, m1, m2, m3, v.w);
    }
    float dp = dpos[kp];
    float d0 = sqrtf(fmaxf(m0, 0.f) + EPSF);
    float d1 = sqrtf(fmaxf(m1, 0.f) + EPSF);
    float d2 = sqrtf(fmaxf(m2, 0.f) + EPSF);
    float d3 = sqrtf(fmaxf(m3, 0.f) + EPSF);
    float l = fmaxf(dp - d0 + MARGINF, 0.f)
            + fmaxf(dp - d1 + MARGINF, 0.f)
            + fmaxf(dp - d2 + MARGINF, 0.f)
            + fmaxf(dp - d3 + MARGINF, 0.f);
#pragma unroll
    for (int off = 32; off; off >>= 1) l += __shfl_xor(l, off, 64);
    if ((threadIdx.x & 63) == 0) s4[threadIdx.x >> 6] = l;
    __syncthreads();
    if (threadIdx.x == 0)
        partials[blockIdx.x] = s4[0] + s4[1] + s4[2] + s4[3];
}

// ---------------------------------------------------------------------------
// Kernel 6: reduce 32 block partials -> mean -> d_out[0]
// ---------------------------------------------------------------------------
__global__ __launch_bounds__(64) void finalize_kernel(const float* __restrict__ partials,
                                                      float* __restrict__ out) {
    int tid = threadIdx.x;
    float v = (tid < 32) ? partials[tid] : 0.f;
#pragma unroll
    for (int off = 32; off; off >>= 1) v += __shfl_xor(v, off, 64);
    if (tid == 0) out[0] = v * (1.0f / (float)(BB * NN * NUM_NEG));
}

extern "C" void kernel_launch(void* const* d_in, const int* in_sizes, int n_in,
                              void* d_out, int out_size, void* d_ws, size_t ws_size,
                              hipStream_t stream) {
    // inputs: 0=kp1 (unused), 1=w_kp1, 2=kp1_desc, 3=desc2, 4=homo12 (unused)
    const float* w_kp1    = (const float*)d_in[1];
    const float* kp1_desc = (const float*)d_in[2];
    const float* desc2    = (const float*)d_in[3];
    float* out = (float*)d_out;

    float* ws = (float*)d_ws;
    float* cells    = ws;                               // B*M*C   = 1,048,576 f
    float* cn       = cells + (size_t)BB * MM * CC;     // B*M     = 16,384 f
    float* dpos     = cn + (size_t)BB * MM;             // B*N     = 8,192 f
    float* an       = dpos + (size_t)BB * NN;           // B*N     = 8,192 f
    float* partials = an + (size_t)BB * NN;             // 32 f
    float* cand     = partials + 64;                    // B*N*32  = 262,144 f
    unsigned short* cells_bf = (unsigned short*)(cand + (size_t)BB * NN * 32); // B*M*C bf16
    unsigned short* kp_bf    = cells_bf + (size_t)BB * MM * CC;                // B*N*C bf16

    pool_kernel<<<dim3(4096), dim3(256), 0, stream>>>(desc2, cells);
    normcells_kernel<<<dim3(4096), dim3(256), 0, stream>>>(cells, cells_bf, cn);
    pos_kernel<<<dim3(2048), dim3(256), 0, stream>>>(w_kp1, kp1_desc, desc2, dpos, an, kp_bf);
    loss_mfma_kernel<<<dim3(256, BB), dim3(256), 0, stream>>>(
        cells_bf, cn, kp_bf, w_kp1, an, cand);
    merge_kernel<<<dim3(BB * NN / 256), dim3(256), 0, stream>>>(cand, dpos, partials);
    finalize_kernel<<<dim3(1), dim3(64), 0, stream>>>(partials, out);
}